// Round 2
// baseline (1816.030 us; speedup 1.0000x reference)
//
#include <hip/hip_runtime.h>
#include <math.h>

namespace {
constexpr int Bc  = 4;
constexpr int Tc  = 2048;
constexpr int Dc  = 1024;
constexpr int Hc  = 16;
constexpr int HDc = 64;
constexpr int N3  = 3 * Dc;                      // 3072
constexpr size_t QKV_ELEMS = (size_t)Bc * Hc * Tc * HDc;  // 8388608 (32 MiB fp32)
}

// ---------------------------------------------------------------------------
// Kernel 1: qkv = x @ w_qkv + b_qkv, scattered into q/k/v [B,H,T,Hd]
// 64x64 tile, BK=16, 256 threads, 4x4 per thread. fp32 VALU.
// ---------------------------------------------------------------------------
__global__ __launch_bounds__(256) void qkv_gemm_kernel(
    const float* __restrict__ x, const float* __restrict__ w,
    const float* __restrict__ bias,
    float* __restrict__ qo, float* __restrict__ ko, float* __restrict__ vo)
{
    __shared__ float As[16][68];   // [k][m], transposed A tile
    __shared__ float Bs[16][68];   // [k][n]
    const int tid = threadIdx.x;
    const int tx  = tid & 15;
    const int ty  = tid >> 4;
    const int m0  = blockIdx.x * 64;
    const int n0  = blockIdx.y * 64;
    const int ar  = tid >> 2;          // 0..63 A-row
    const int ac  = (tid & 3) << 2;    // 0,4,8,12 k-chunk
    const int br  = tid >> 4;          // 0..15 B-row
    const int bc  = (tid & 15) << 2;   // 0..60 n-chunk

    const float* xrow = x + (size_t)(m0 + ar) * Dc + ac;
    const float* wrow = w + (size_t)br * N3 + n0 + bc;

    float acc[4][4] = {};

    for (int k0 = 0; k0 < Dc; k0 += 16) {
        float4 av = *(const float4*)(xrow + k0);
        float4 bv = *(const float4*)(wrow + (size_t)k0 * N3);
        As[ac + 0][ar] = av.x;
        As[ac + 1][ar] = av.y;
        As[ac + 2][ar] = av.z;
        As[ac + 3][ar] = av.w;
        *(float4*)&Bs[br][bc] = bv;
        __syncthreads();
#pragma unroll
        for (int kk = 0; kk < 16; ++kk) {
            float a[4], b[4];
#pragma unroll
            for (int i = 0; i < 4; ++i) a[i] = As[kk][ty * 4 + i];
#pragma unroll
            for (int j = 0; j < 4; ++j) b[j] = Bs[kk][tx * 4 + j];
#pragma unroll
            for (int i = 0; i < 4; ++i)
#pragma unroll
                for (int j = 0; j < 4; ++j)
                    acc[i][j] = fmaf(a[i], b[j], acc[i][j]);
        }
        __syncthreads();
    }

    // Epilogue: n0 is 64-aligned -> whole tile belongs to one (q/k/v, head).
    const int which = n0 >> 10;             // 0=q 1=k 2=v
    const int h     = (n0 & 1023) >> 6;     // head
    float* dst = (which == 0) ? qo : ((which == 1) ? ko : vo);
    float4 bi4 = *(const float4*)(bias + n0 + (tx << 2));
#pragma unroll
    for (int i = 0; i < 4; ++i) {
        int m = m0 + ty * 4 + i;
        int b = m >> 11;          // / 2048
        int t = m & 2047;
        float4 o4;
        o4.x = acc[i][0] + bi4.x;
        o4.y = acc[i][1] + bi4.y;
        o4.z = acc[i][2] + bi4.z;
        o4.w = acc[i][3] + bi4.w;
        *(float4*)(dst + ((size_t)(b * Hc + h) * Tc + t) * HDc + (tx << 2)) = o4;
    }
}

// ---------------------------------------------------------------------------
// Kernel 2: causal flash attention, fp32. One block = one (b,h,q-block of 64).
// 256 threads as 16x16 grid, each thread owns 4 rows x 4 cols.
// LDS: Qt + Vs + KP where KP serves as K^T during QK^T and as P during PV
// (disjoint lifetimes; extra barrier separates them). 52 KB -> 3 blocks/CU.
// O is written into the Q buffer (exclusive per-block region, Q already in LDS).
// ---------------------------------------------------------------------------
__global__ __launch_bounds__(256) void flash_kernel(
    const float* __restrict__ q, const float* __restrict__ k,
    const float* __restrict__ v, float* __restrict__ o)
{
    __shared__ float Qt[64][68];   // [d][r] transposed
    __shared__ float KP[64][68];   // phase 1: K^T [d][c]; phase 2: P [r][c]
    __shared__ float Vs[64][68];   // [c][d] natural

    const int tid = threadIdx.x;
    const int tx  = tid & 15;
    const int ty  = tid >> 4;
    const int idx = blockIdx.x;
    const int qb  = 31 - (idx & 31);   // descending: heavy q-blocks first
    const int bh  = idx >> 5;          // 0..63 = b*H+h

    const float* qptr = q + (size_t)bh * Tc * HDc;
    const float* kptr = k + (size_t)bh * Tc * HDc;
    const float* vptr = v + (size_t)bh * Tc * HDc;

    // Stage Q tile (transposed). Visibility via the barriers before QK^T.
    for (int i = tid; i < 1024; i += 256) {
        int r  = i >> 4;
        int c4 = (i & 15) << 2;
        float4 t4 = *(const float4*)(qptr + (size_t)(qb * 64 + r) * HDc + c4);
        Qt[c4 + 0][r] = t4.x;
        Qt[c4 + 1][r] = t4.y;
        Qt[c4 + 2][r] = t4.z;
        Qt[c4 + 3][r] = t4.w;
    }

    float acc[4][4] = {};
    float mi[4] = {-INFINITY, -INFINITY, -INFINITY, -INFINITY};
    float li[4] = {0.f, 0.f, 0.f, 0.f};
    const float scale = 0.125f;   // 1/sqrt(64)

    for (int kt = 0; kt <= qb; ++kt) {
        __syncthreads();   // prior iteration's KP/Vs reads complete
        for (int i = tid; i < 1024; i += 256) {
            int r  = i >> 4;
            int c4 = (i & 15) << 2;
            float4 k4 = *(const float4*)(kptr + (size_t)(kt * 64 + r) * HDc + c4);
            float4 v4 = *(const float4*)(vptr + (size_t)(kt * 64 + r) * HDc + c4);
            KP[c4 + 0][r] = k4.x;
            KP[c4 + 1][r] = k4.y;
            KP[c4 + 2][r] = k4.z;
            KP[c4 + 3][r] = k4.w;
            *(float4*)&Vs[r][c4] = v4;
        }
        __syncthreads();

        // S = scale * Q K^T  (4x4 per thread)
        float s[4][4] = {};
#pragma unroll 8
        for (int d = 0; d < 64; ++d) {
            float4 a4 = *(const float4*)&Qt[d][ty << 2];
            float4 b4 = *(const float4*)&KP[d][tx << 2];
            s[0][0] = fmaf(a4.x, b4.x, s[0][0]);
            s[0][1] = fmaf(a4.x, b4.y, s[0][1]);
            s[0][2] = fmaf(a4.x, b4.z, s[0][2]);
            s[0][3] = fmaf(a4.x, b4.w, s[0][3]);
            s[1][0] = fmaf(a4.y, b4.x, s[1][0]);
            s[1][1] = fmaf(a4.y, b4.y, s[1][1]);
            s[1][2] = fmaf(a4.y, b4.z, s[1][2]);
            s[1][3] = fmaf(a4.y, b4.w, s[1][3]);
            s[2][0] = fmaf(a4.z, b4.x, s[2][0]);
            s[2][1] = fmaf(a4.z, b4.y, s[2][1]);
            s[2][2] = fmaf(a4.z, b4.z, s[2][2]);
            s[2][3] = fmaf(a4.z, b4.w, s[2][3]);
            s[3][0] = fmaf(a4.w, b4.x, s[3][0]);
            s[3][1] = fmaf(a4.w, b4.y, s[3][1]);
            s[3][2] = fmaf(a4.w, b4.z, s[3][2]);
            s[3][3] = fmaf(a4.w, b4.w, s[3][3]);
        }
        __syncthreads();   // all K^T reads done; KP may now become P

#pragma unroll
        for (int i = 0; i < 4; ++i)
#pragma unroll
            for (int j = 0; j < 4; ++j) s[i][j] *= scale;

        if (kt == qb) {   // diagonal tile: mask kcol > qrow
#pragma unroll
            for (int i = 0; i < 4; ++i)
#pragma unroll
                for (int j = 0; j < 4; ++j)
                    if (tx * 4 + j > ty * 4 + i) s[i][j] = -INFINITY;
        }

        // Online softmax per row (row owned by 16 contiguous lanes)
#pragma unroll
        for (int i = 0; i < 4; ++i) {
            float rm = fmaxf(fmaxf(s[i][0], s[i][1]), fmaxf(s[i][2], s[i][3]));
#pragma unroll
            for (int off = 8; off; off >>= 1)
                rm = fmaxf(rm, __shfl_xor(rm, off, 16));
            float mnew = fmaxf(mi[i], rm);
            float sc   = __expf(mi[i] - mnew);   // first tile: exp(-inf)=0
            float rs   = 0.f;
#pragma unroll
            for (int j = 0; j < 4; ++j) {
                s[i][j] = __expf(s[i][j] - mnew);
                rs += s[i][j];
            }
#pragma unroll
            for (int off = 8; off; off >>= 1)
                rs += __shfl_xor(rs, off, 16);
            li[i] = li[i] * sc + rs;
            mi[i] = mnew;
#pragma unroll
            for (int j = 0; j < 4; ++j) acc[i][j] *= sc;
            float4 p4;
            p4.x = s[i][0]; p4.y = s[i][1]; p4.z = s[i][2]; p4.w = s[i][3];
            *(float4*)&KP[ty * 4 + i][tx << 2] = p4;   // KP now holds P
        }
        __syncthreads();

        // O += P @ V
#pragma unroll 4
        for (int c = 0; c < 64; ++c) {
            float4 v4 = *(const float4*)&Vs[c][tx << 2];
            float p0 = KP[ty * 4 + 0][c];
            float p1 = KP[ty * 4 + 1][c];
            float p2 = KP[ty * 4 + 2][c];
            float p3 = KP[ty * 4 + 3][c];
            acc[0][0] = fmaf(p0, v4.x, acc[0][0]);
            acc[0][1] = fmaf(p0, v4.y, acc[0][1]);
            acc[0][2] = fmaf(p0, v4.z, acc[0][2]);
            acc[0][3] = fmaf(p0, v4.w, acc[0][3]);
            acc[1][0] = fmaf(p1, v4.x, acc[1][0]);
            acc[1][1] = fmaf(p1, v4.y, acc[1][1]);
            acc[1][2] = fmaf(p1, v4.z, acc[1][2]);
            acc[1][3] = fmaf(p1, v4.w, acc[1][3]);
            acc[2][0] = fmaf(p2, v4.x, acc[2][0]);
            acc[2][1] = fmaf(p2, v4.y, acc[2][1]);
            acc[2][2] = fmaf(p2, v4.z, acc[2][2]);
            acc[2][3] = fmaf(p2, v4.w, acc[2][3]);
            acc[3][0] = fmaf(p3, v4.x, acc[3][0]);
            acc[3][1] = fmaf(p3, v4.y, acc[3][1]);
            acc[3][2] = fmaf(p3, v4.z, acc[3][2]);
            acc[3][3] = fmaf(p3, v4.w, acc[3][3]);
        }
    }

    // Final normalize + write O [B,H,T,Hd] (o aliases the Q buffer: this
    // block's region was fully staged to LDS and is exclusively ours).
#pragma unroll
    for (int i = 0; i < 4; ++i) {
        float inv = 1.0f / li[i];
        float4 o4;
        o4.x = acc[i][0] * inv;
        o4.y = acc[i][1] * inv;
        o4.z = acc[i][2] * inv;
        o4.w = acc[i][3] * inv;
        *(float4*)(o + ((size_t)bh * Tc + qb * 64 + ty * 4 + i) * HDc + (tx << 2)) = o4;
    }
}

// ---------------------------------------------------------------------------
// Kernel 3: out = gather(o)[B,T,D] @ w_proj + b_proj
// Same GEMM skeleton; A is gathered from [B,H,T,Hd] on the fly.
// ---------------------------------------------------------------------------
__global__ __launch_bounds__(256) void proj_gemm_kernel(
    const float* __restrict__ a, const float* __restrict__ w,
    const float* __restrict__ bias, float* __restrict__ out)
{
    __shared__ float As[16][68];
    __shared__ float Bs[16][68];
    const int tid = threadIdx.x;
    const int tx  = tid & 15;
    const int ty  = tid >> 4;
    const int m0  = blockIdx.x * 64;
    const int n0  = blockIdx.y * 64;
    const int ar  = tid >> 2;
    const int ac  = (tid & 3) << 2;
    const int br  = tid >> 4;
    const int bc  = (tid & 15) << 2;

    const int am = m0 + ar;
    const int ab = am >> 11;       // batch
    const int at = am & 2047;      // time

    float acc[4][4] = {};

    for (int k0 = 0; k0 < Dc; k0 += 16) {
        const int h    = k0 >> 6;              // BK=16 never crosses a head
        const int dsub = (k0 & 63) + ac;
        float4 av = *(const float4*)(a + ((size_t)(ab * Hc + h) * Tc + at) * HDc + dsub);
        float4 bv = *(const float4*)(w + (size_t)(k0 + br) * Dc + n0 + bc);
        As[ac + 0][ar] = av.x;
        As[ac + 1][ar] = av.y;
        As[ac + 2][ar] = av.z;
        As[ac + 3][ar] = av.w;
        *(float4*)&Bs[br][bc] = bv;
        __syncthreads();
#pragma unroll
        for (int kk = 0; kk < 16; ++kk) {
            float aa[4], bb[4];
#pragma unroll
            for (int i = 0; i < 4; ++i) aa[i] = As[kk][ty * 4 + i];
#pragma unroll
            for (int j = 0; j < 4; ++j) bb[j] = Bs[kk][tx * 4 + j];
#pragma unroll
            for (int i = 0; i < 4; ++i)
#pragma unroll
                for (int j = 0; j < 4; ++j)
                    acc[i][j] = fmaf(aa[i], bb[j], acc[i][j]);
        }
        __syncthreads();
    }

    float4 bi4 = *(const float4*)(bias + n0 + (tx << 2));
#pragma unroll
    for (int i = 0; i < 4; ++i) {
        float4 o4;
        o4.x = acc[i][0] + bi4.x;
        o4.y = acc[i][1] + bi4.y;
        o4.z = acc[i][2] + bi4.z;
        o4.w = acc[i][3] + bi4.w;
        *(float4*)(out + (size_t)(m0 + ty * 4 + i) * Dc + n0 + (tx << 2)) = o4;
    }
}

// ---------------------------------------------------------------------------
extern "C" void kernel_launch(void* const* d_in, const int* in_sizes, int n_in,
                              void* d_out, int out_size, void* d_ws, size_t ws_size,
                              hipStream_t stream) {
    const float* x      = (const float*)d_in[0];
    const float* w_qkv  = (const float*)d_in[1];
    const float* b_qkv  = (const float*)d_in[2];
    const float* w_proj = (const float*)d_in[3];
    const float* b_proj = (const float*)d_in[4];
    float* out = (float*)d_out;

    // Workspace: 3 buffers of 32 MiB (q, k, v). O overwrites the q buffer.
    float* qw = (float*)d_ws;
    float* kw = qw + QKV_ELEMS;
    float* vw = kw + QKV_ELEMS;
    float* ow = qw;   // flash output reuses the Q buffer (safe, see kernel)

    qkv_gemm_kernel<<<dim3(128, 48), 256, 0, stream>>>(x, w_qkv, b_qkv, qw, kw, vw);
    flash_kernel<<<dim3(2048), 256, 0, stream>>>(qw, kw, vw, ow);
    proj_gemm_kernel<<<dim3(128, 16), 256, 0, stream>>>(ow, w_proj, b_proj, out);
}

// Round 3
// 419.925 us; speedup vs baseline: 4.3246x; 4.3246x over previous
//
#include <hip/hip_runtime.h>
#include <math.h>
#include <stdint.h>

typedef unsigned short u16;
typedef __bf16 bf16x8 __attribute__((ext_vector_type(8)));
typedef float  f32x4  __attribute__((ext_vector_type(4)));

#define AS1 __attribute__((address_space(1)))
#define AS3 __attribute__((address_space(3)))

__device__ __forceinline__ void gld_lds16(const void* g, void* l) {
    // async global->LDS, 16B per lane; LDS dest = wave-uniform base + lane*16
    __builtin_amdgcn_global_load_lds((AS1 const uint32_t*)g, (AS3 uint32_t*)l, 16, 0, 0);
}

__device__ __forceinline__ u16 f2bf(float f) {   // RNE, no NaN handling needed
    unsigned u = __float_as_uint(f);
    unsigned r = u + 0x7fffu + ((u >> 16) & 1u);
    return (u16)(r >> 16);
}

namespace {
constexpr int Tc  = 2048;
constexpr int Dc  = 1024;
constexpr int Hc  = 16;
constexpr size_t QE = 8388608;   // B*H*T*64 elems
}

// ---------------------------------------------------------------------------
// fp32 -> bf16 flat convert (8 elems/thread)
// ---------------------------------------------------------------------------
__global__ __launch_bounds__(256) void cvt_bf16(const float* __restrict__ in,
                                                u16* __restrict__ out, int n8) {
    int i = blockIdx.x * 256 + threadIdx.x;
    if (i >= n8) return;
    const float4* p = (const float4*)in + (size_t)i * 2;
    float4 a = p[0], b = p[1];
    union { u16 u[8]; uint4 v; } r;
    r.u[0] = f2bf(a.x); r.u[1] = f2bf(a.y); r.u[2] = f2bf(a.z); r.u[3] = f2bf(a.w);
    r.u[4] = f2bf(b.x); r.u[5] = f2bf(b.y); r.u[6] = f2bf(b.z); r.u[7] = f2bf(b.w);
    ((uint4*)out)[i] = r.v;
}

// ---------------------------------------------------------------------------
// fp32 [K][N] -> bf16 [N][K] transpose-convert, 64x64 tiles
// ---------------------------------------------------------------------------
__global__ __launch_bounds__(256) void cvtT(const float* __restrict__ in,
                                            u16* __restrict__ out, int K, int N) {
    __shared__ u16 t[64][72];
    const int n0 = blockIdx.x * 64, k0 = blockIdx.y * 64;
    const int tid = threadIdx.x;
    const int r = tid >> 2, c0 = (tid & 3) << 4;
    const float* src = in + (size_t)(k0 + r) * N + n0 + c0;
#pragma unroll
    for (int j = 0; j < 16; j += 4) {
        float4 f = *(const float4*)(src + j);
        t[r][c0 + j + 0] = f2bf(f.x);
        t[r][c0 + j + 1] = f2bf(f.y);
        t[r][c0 + j + 2] = f2bf(f.z);
        t[r][c0 + j + 3] = f2bf(f.w);
    }
    __syncthreads();
    u16* dst = out + (size_t)(n0 + r) * K + k0 + c0;
    union { u16 u[8]; uint4 v; } o1, o2;
#pragma unroll
    for (int j = 0; j < 8; ++j) o1.u[j] = t[c0 + j][r];
#pragma unroll
    for (int j = 0; j < 8; ++j) o2.u[j] = t[c0 + 8 + j][r];
    *(uint4*)dst = o1.v;
    *(uint4*)(dst + 8) = o2.v;
}

// ---------------------------------------------------------------------------
// QKV GEMM: [8192,1024]bf16 @ [1024,3072] (B^T layout [3072][1024]) -> q/k/vT
// 128x128 tile, BK=32, 4 waves (2x2 quadrants of 64x64), 16x16x32 MFMA.
// LDS tiles [128 rows][32 k] bf16, 64B rows, swizzle col16 ^= (row>>1)&3.
// ---------------------------------------------------------------------------
__global__ __launch_bounds__(256) void qkv_gemm_bf16(
    const u16* __restrict__ xb, const u16* __restrict__ wT,
    const float* __restrict__ bias,
    u16* __restrict__ qo, u16* __restrict__ ko, u16* __restrict__ vt)
{
    __shared__ u16 At[2][4096];
    __shared__ u16 Bt[2][4096];

    const int tid  = threadIdx.x;
    const int lane = tid & 63;
    const int wv   = tid >> 6;
    const int wr   = wv >> 1;
    const int wc   = wv & 1;
    const int m0   = blockIdx.x * 128;
    const int n0   = blockIdx.y * 128;

    // staging: 512 chunks of 16B; chunk p -> row=p>>2, cp=p&3, col16=cp^((row>>1)&3)
    const int p1 = wv * 128 + lane, p2 = p1 + 64;
    const int r1 = p1 >> 2, c1 = (p1 & 3) ^ ((r1 >> 1) & 3);
    const int r2 = p2 >> 2, c2 = (p2 & 3) ^ ((r2 >> 1) & 3);

    const u16* ga1 = xb + (size_t)(m0 + r1) * 1024 + c1 * 8;
    const u16* ga2 = xb + (size_t)(m0 + r2) * 1024 + c2 * 8;
    const u16* gb1 = wT + (size_t)(n0 + r1) * 1024 + c1 * 8;
    const u16* gb2 = wT + (size_t)(n0 + r2) * 1024 + c2 * 8;

    f32x4 acc[4][4] = {};

#define STAGE_G(buf, k0)                                   \
    do {                                                   \
        gld_lds16(ga1 + (k0), &At[buf][wv * 1024]);        \
        gld_lds16(ga2 + (k0), &At[buf][wv * 1024 + 512]);  \
        gld_lds16(gb1 + (k0), &Bt[buf][wv * 1024]);        \
        gld_lds16(gb2 + (k0), &Bt[buf][wv * 1024 + 512]);  \
    } while (0)

    STAGE_G(0, 0);
    asm volatile("s_waitcnt vmcnt(0)" ::: "memory");
    __syncthreads();

    int cur = 0;
    for (int t = 0; t < 32; ++t) {
        if (t < 31) STAGE_G(cur ^ 1, (t + 1) * 32);
        bf16x8 af[4], bfr[4];
#pragma unroll
        for (int i = 0; i < 4; ++i) {
            int row = wr * 64 + i * 16 + (lane & 15);
            int c   = (lane >> 4) ^ ((row >> 1) & 3);
            af[i] = *(const bf16x8*)&At[cur][row * 32 + c * 8];
            int rowb = wc * 64 + i * 16 + (lane & 15);
            int cb   = (lane >> 4) ^ ((rowb >> 1) & 3);
            bfr[i] = *(const bf16x8*)&Bt[cur][rowb * 32 + cb * 8];
        }
#pragma unroll
        for (int i = 0; i < 4; ++i)
#pragma unroll
            for (int j = 0; j < 4; ++j)
                acc[i][j] = __builtin_amdgcn_mfma_f32_16x16x32_bf16(
                    af[i], bfr[j], acc[i][j], 0, 0, 0);
        asm volatile("s_waitcnt vmcnt(0)" ::: "memory");
        __syncthreads();
        cur ^= 1;
    }
#undef STAGE_G

    // epilogue: C/D layout col=lane&15, row=(lane>>4)*4+reg
    const int nq = n0 + wc * 64;          // 64-aligned -> one (q/k/v, head)
    const int which = nq >> 10;
    const int h  = (nq & 1023) >> 6;
    const int rr = (lane >> 4) * 4;
    const int cl = lane & 15;

    if (which < 2) {
        u16* dst = which ? ko : qo;
#pragma unroll
        for (int i = 0; i < 4; ++i)
#pragma unroll
            for (int j = 0; j < 4; ++j) {
                int d = j * 16 + cl;
                float bv = bias[nq + d];
#pragma unroll
                for (int r = 0; r < 4; ++r) {
                    int m = m0 + wr * 64 + i * 16 + rr + r;
                    int b = m >> 11, tt = m & 2047;
                    dst[(((size_t)(b * Hc + h)) * Tc + tt) * 64 + d] =
                        f2bf(acc[i][j][r] + bv);
                }
            }
    } else {
        // V stored TRANSPOSED: vt[bh][d][t]
#pragma unroll
        for (int i = 0; i < 4; ++i) {
            int m = m0 + wr * 64 + i * 16 + rr;   // +r are 4 consecutive tokens
            int b = m >> 11, tt = m & 2047;
#pragma unroll
            for (int j = 0; j < 4; ++j) {
                int d = j * 16 + cl;
                float bv = bias[nq + d];
                union { u16 u[4]; uint2 v2; } pk;
#pragma unroll
                for (int r = 0; r < 4; ++r) pk.u[r] = f2bf(acc[i][j][r] + bv);
                *(uint2*)&vt[((size_t)(b * Hc + h) * 64 + d) * Tc + tt] = pk.v2;
            }
        }
    }
}

// ---------------------------------------------------------------------------
// Flash attention, bf16 MFMA. Block = (bh, qb of 64 rows); 4 waves x 16 q-rows.
// K tiles [key][d], Vt tiles [d][key], Q [q][d]: all 64x64 bf16, 128B rows,
// swizzle col16 ^= row&7. P round-trips through swizzled LDS (per-wave region).
// ---------------------------------------------------------------------------
__global__ __launch_bounds__(256) void flash_mfma(
    const u16* __restrict__ qg, const u16* __restrict__ kg,
    const u16* __restrict__ vtg, u16* __restrict__ og)
{
    __shared__ u16 Qs[4096];
    __shared__ u16 Ks[2][4096];
    __shared__ u16 Vs[2][4096];
    __shared__ u16 Ps[4096];

    const int tid  = threadIdx.x;
    const int lane = tid & 63;
    const int wv   = tid >> 6;
    const int qb   = 31 - (blockIdx.x & 31);
    const int bh   = blockIdx.x >> 5;

    // staging: chunk p -> row=p>>3, cp=p&7, col16 = cp ^ (row&7)
    const int p1 = wv * 128 + lane, p2 = p1 + 64;
    const int r1 = p1 >> 3, c1 = (p1 & 7) ^ (r1 & 7);
    const int r2 = p2 >> 3, c2 = (p2 & 7) ^ (r2 & 7);

    const size_t tb = (size_t)bh * Tc;
    const u16* kb1 = kg + (tb + r1) * 64 + c1 * 8;
    const u16* kb2 = kg + (tb + r2) * 64 + c2 * 8;
    const u16* vb1 = vtg + ((size_t)bh * 64 + r1) * Tc + c1 * 8;
    const u16* vb2 = vtg + ((size_t)bh * 64 + r2) * Tc + c2 * 8;

    gld_lds16(qg + (tb + (size_t)qb * 64 + r1) * 64 + c1 * 8, &Qs[wv * 1024]);
    gld_lds16(qg + (tb + (size_t)qb * 64 + r2) * 64 + c2 * 8, &Qs[wv * 1024 + 512]);
    gld_lds16(kb1, &Ks[0][wv * 1024]);
    gld_lds16(kb2, &Ks[0][wv * 1024 + 512]);
    gld_lds16(vb1, &Vs[0][wv * 1024]);
    gld_lds16(vb2, &Vs[0][wv * 1024 + 512]);
    asm volatile("s_waitcnt vmcnt(0)" ::: "memory");
    __syncthreads();

    f32x4 accO[4] = {};
    float mi[4] = {-INFINITY, -INFINITY, -INFINITY, -INFINITY};
    float li[4] = {0.f, 0.f, 0.f, 0.f};
    const float scale = 0.125f;
    int cur = 0;

    for (int kt = 0; kt <= qb; ++kt) {
        if (kt < qb) {
            int nx = kt + 1;
            gld_lds16(kb1 + (size_t)nx * 4096, &Ks[cur ^ 1][wv * 1024]);
            gld_lds16(kb2 + (size_t)nx * 4096, &Ks[cur ^ 1][wv * 1024 + 512]);
            gld_lds16(vb1 + nx * 64, &Vs[cur ^ 1][wv * 1024]);
            gld_lds16(vb2 + nx * 64, &Vs[cur ^ 1][wv * 1024 + 512]);
        }

        // ---- S = Q K^T (per wave: 16 q-rows x 64 keys), k-dim = d (2 steps)
        f32x4 s4[4] = {};
#pragma unroll
        for (int ks = 0; ks < 2; ++ks) {
            int arow = wv * 16 + (lane & 15);
            int ac   = (ks * 4 + (lane >> 4)) ^ (arow & 7);
            bf16x8 aq = *(const bf16x8*)&Qs[arow * 64 + ac * 8];
#pragma unroll
            for (int nf = 0; nf < 4; ++nf) {
                int brow = nf * 16 + (lane & 15);
                int bc   = (ks * 4 + (lane >> 4)) ^ (brow & 7);
                bf16x8 bk = *(const bf16x8*)&Ks[cur][brow * 64 + bc * 8];
                s4[nf] = __builtin_amdgcn_mfma_f32_16x16x32_bf16(aq, bk, s4[nf], 0, 0, 0);
            }
        }

        if (kt == qb) {   // diagonal mask: key > q
#pragma unroll
            for (int nf = 0; nf < 4; ++nf)
#pragma unroll
                for (int r = 0; r < 4; ++r)
                    if (nf * 16 + (lane & 15) > wv * 16 + (lane >> 4) * 4 + r)
                        s4[nf][r] = -INFINITY;
        }

        // ---- online softmax (rows owned by 16-lane groups)
#pragma unroll
        for (int r = 0; r < 4; ++r) {
            float v0 = s4[0][r] * scale, v1 = s4[1][r] * scale;
            float v2 = s4[2][r] * scale, v3 = s4[3][r] * scale;
            float rm = fmaxf(fmaxf(v0, v1), fmaxf(v2, v3));
#pragma unroll
            for (int off = 8; off; off >>= 1) rm = fmaxf(rm, __shfl_xor(rm, off, 16));
            float mnew = fmaxf(mi[r], rm);
            float sc = __expf(mi[r] - mnew);
            float p0 = __expf(v0 - mnew), p1 = __expf(v1 - mnew);
            float p2 = __expf(v2 - mnew), p3 = __expf(v3 - mnew);
            float rs = p0 + p1 + p2 + p3;
#pragma unroll
            for (int off = 8; off; off >>= 1) rs += __shfl_xor(rs, off, 16);
            li[r] = li[r] * sc + rs;
            mi[r] = mnew;
#pragma unroll
            for (int df = 0; df < 4; ++df) accO[df][r] *= sc;

            int row = wv * 16 + (lane >> 4) * 4 + r;
            int rb  = row * 64;
            int k0c = lane & 15;
            Ps[rb + (((0 * 16 + k0c) >> 3) ^ (row & 7)) * 8 + (k0c & 7)] = f2bf(p0);
            Ps[rb + (((1 * 16 + k0c) >> 3) ^ (row & 7)) * 8 + (k0c & 7)] = f2bf(p1);
            Ps[rb + (((2 * 16 + k0c) >> 3) ^ (row & 7)) * 8 + (k0c & 7)] = f2bf(p2);
            Ps[rb + (((3 * 16 + k0c) >> 3) ^ (row & 7)) * 8 + (k0c & 7)] = f2bf(p3);
        }

        // ---- O += P V  (k-dim = keys, 2 steps); P reads are wave-local
#pragma unroll
        for (int ks = 0; ks < 2; ++ks) {
            int arow = wv * 16 + (lane & 15);
            int ac   = (ks * 4 + (lane >> 4)) ^ (arow & 7);
            bf16x8 ap = *(const bf16x8*)&Ps[arow * 64 + ac * 8];
#pragma unroll
            for (int df = 0; df < 4; ++df) {
                int brow = df * 16 + (lane & 15);
                int bc   = (ks * 4 + (lane >> 4)) ^ (brow & 7);
                bf16x8 bv = *(const bf16x8*)&Vs[cur][brow * 64 + bc * 8];
                accO[df] = __builtin_amdgcn_mfma_f32_16x16x32_bf16(ap, bv, accO[df], 0, 0, 0);
            }
        }

        asm volatile("s_waitcnt vmcnt(0)" ::: "memory");
        __syncthreads();
        cur ^= 1;
    }

#pragma unroll
    for (int r = 0; r < 4; ++r) {
        float inv = 1.0f / li[r];
        int t = qb * 64 + wv * 16 + (lane >> 4) * 4 + r;
#pragma unroll
        for (int df = 0; df < 4; ++df) {
            int d = df * 16 + (lane & 15);
            og[(tb + t) * 64 + d] = f2bf(accO[df][r] * inv);
        }
    }
}

// ---------------------------------------------------------------------------
// Proj GEMM: gather(O [bh][t][64]) @ w_projT [1024][1024] + b -> out fp32
// ---------------------------------------------------------------------------
__global__ __launch_bounds__(256) void proj_gemm_bf16(
    const u16* __restrict__ ob, const u16* __restrict__ wT,
    const float* __restrict__ bias, float* __restrict__ out)
{
    __shared__ u16 At[2][4096];
    __shared__ u16 Bt[2][4096];

    const int tid  = threadIdx.x;
    const int lane = tid & 63;
    const int wv   = tid >> 6;
    const int wr   = wv >> 1;
    const int wc   = wv & 1;
    const int m0   = blockIdx.x * 128;
    const int n0   = blockIdx.y * 128;

    const int p1 = wv * 128 + lane, p2 = p1 + 64;
    const int r1 = p1 >> 2, c1 = (p1 & 3) ^ ((r1 >> 1) & 3);
    const int r2 = p2 >> 2, c2 = (p2 & 3) ^ ((r2 >> 1) & 3);

    const int m1 = m0 + r1, m2 = m0 + r2;
    const size_t ab1 = ((size_t)(m1 >> 11) * Hc) * Tc + (m1 & 2047);  // b*16*2048 + t
    const size_t ab2 = ((size_t)(m2 >> 11) * Hc) * Tc + (m2 & 2047);
    const u16* gb1 = wT + (size_t)(n0 + r1) * 1024 + c1 * 8;
    const u16* gb2 = wT + (size_t)(n0 + r2) * 1024 + c2 * 8;

    f32x4 acc[4][4] = {};

#define STAGE_P(buf, k0)                                                          \
    do {                                                                          \
        int kk1 = (k0) + c1 * 8, kk2 = (k0) + c2 * 8;                             \
        gld_lds16(ob + (ab1 + (size_t)(kk1 >> 6) * Tc) * 64 + (kk1 & 63),         \
                  &At[buf][wv * 1024]);                                           \
        gld_lds16(ob + (ab2 + (size_t)(kk2 >> 6) * Tc) * 64 + (kk2 & 63),         \
                  &At[buf][wv * 1024 + 512]);                                     \
        gld_lds16(gb1 + (k0), &Bt[buf][wv * 1024]);                               \
        gld_lds16(gb2 + (k0), &Bt[buf][wv * 1024 + 512]);                         \
    } while (0)

    STAGE_P(0, 0);
    asm volatile("s_waitcnt vmcnt(0)" ::: "memory");
    __syncthreads();

    int cur = 0;
    for (int t = 0; t < 32; ++t) {
        if (t < 31) STAGE_P(cur ^ 1, (t + 1) * 32);
        bf16x8 af[4], bfr[4];
#pragma unroll
        for (int i = 0; i < 4; ++i) {
            int row = wr * 64 + i * 16 + (lane & 15);
            int c   = (lane >> 4) ^ ((row >> 1) & 3);
            af[i] = *(const bf16x8*)&At[cur][row * 32 + c * 8];
            int rowb = wc * 64 + i * 16 + (lane & 15);
            int cb   = (lane >> 4) ^ ((rowb >> 1) & 3);
            bfr[i] = *(const bf16x8*)&Bt[cur][rowb * 32 + cb * 8];
        }
#pragma unroll
        for (int i = 0; i < 4; ++i)
#pragma unroll
            for (int j = 0; j < 4; ++j)
                acc[i][j] = __builtin_amdgcn_mfma_f32_16x16x32_bf16(
                    af[i], bfr[j], acc[i][j], 0, 0, 0);
        asm volatile("s_waitcnt vmcnt(0)" ::: "memory");
        __syncthreads();
        cur ^= 1;
    }
#undef STAGE_P

    const int rr = (lane >> 4) * 4;
    const int cl = lane & 15;
#pragma unroll
    for (int i = 0; i < 4; ++i)
#pragma unroll
        for (int j = 0; j < 4; ++j) {
            int n = n0 + wc * 64 + j * 16 + cl;
            float bv = bias[n];
#pragma unroll
            for (int r = 0; r < 4; ++r) {
                int m = m0 + wr * 64 + i * 16 + rr + r;
                out[(size_t)m * 1024 + n] = acc[i][j][r] + bv;
            }
        }
}

// ---------------------------------------------------------------------------
extern "C" void kernel_launch(void* const* d_in, const int* in_sizes, int n_in,
                              void* d_out, int out_size, void* d_ws, size_t ws_size,
                              hipStream_t stream) {
    const float* x      = (const float*)d_in[0];
    const float* w_qkv  = (const float*)d_in[1];
    const float* b_qkv  = (const float*)d_in[2];
    const float* w_proj = (const float*)d_in[3];
    const float* b_proj = (const float*)d_in[4];
    float* out = (float*)d_out;

    u16* xb     = (u16*)d_ws;            // 16 MiB
    u16* wqkvT  = xb + QE;               // 6 MiB
    u16* wprojT = wqkvT + 3145728;       // 2 MiB
    u16* qb16   = wprojT + 1048576;      // 16 MiB
    u16* kb16   = qb16 + QE;             // 16 MiB
    u16* vtb    = kb16 + QE;             // 16 MiB (V transposed [bh][d][t])
    u16* ob16   = vtb + QE;              // 16 MiB — total 88 MiB

    cvt_bf16<<<4096, 256, 0, stream>>>(x, xb, 1048576);
    cvtT<<<dim3(48, 16), 256, 0, stream>>>(w_qkv, wqkvT, 1024, 3072);
    cvtT<<<dim3(16, 16), 256, 0, stream>>>(w_proj, wprojT, 1024, 1024);
    qkv_gemm_bf16<<<dim3(64, 24), 256, 0, stream>>>(xb, wqkvT, b_qkv, qb16, kb16, vtb);
    flash_mfma<<<2048, 256, 0, stream>>>(qb16, kb16, vtb, ob16);
    proj_gemm_bf16<<<dim3(64, 8), 256, 0, stream>>>(ob16, wprojT, b_proj, out);
}

// Round 4
// 346.776 us; speedup vs baseline: 5.2369x; 1.2109x over previous
//
#include <hip/hip_runtime.h>
#include <math.h>
#include <stdint.h>

typedef unsigned short u16;
typedef __bf16 bf16x8 __attribute__((ext_vector_type(8)));
typedef float  f32x4  __attribute__((ext_vector_type(4)));

#define AS1 __attribute__((address_space(1)))
#define AS3 __attribute__((address_space(3)))

__device__ __forceinline__ void gld_lds16(const void* g, void* l) {
    // async global->LDS, 16B per lane; LDS dest = wave-uniform base + lane*16
    __builtin_amdgcn_global_load_lds((AS1 const uint32_t*)g, (AS3 uint32_t*)l, 16, 0, 0);
}

__device__ __forceinline__ u16 f2bf(float f) {   // RNE
    unsigned u = __float_as_uint(f);
    unsigned r = u + 0x7fffu + ((u >> 16) & 1u);
    return (u16)(r >> 16);
}

namespace {
constexpr int Tc  = 2048;
constexpr int Hc  = 16;
constexpr size_t QE = 8388608;   // B*H*T*64 elems
}

// ---------------------------------------------------------------------------
// fp32 -> bf16 flat convert (8 elems/thread)
// ---------------------------------------------------------------------------
__global__ __launch_bounds__(256) void cvt_bf16(const float* __restrict__ in,
                                                u16* __restrict__ out, int n8) {
    int i = blockIdx.x * 256 + threadIdx.x;
    if (i >= n8) return;
    const float4* p = (const float4*)in + (size_t)i * 2;
    float4 a = p[0], b = p[1];
    union { u16 u[8]; uint4 v; } r;
    r.u[0] = f2bf(a.x); r.u[1] = f2bf(a.y); r.u[2] = f2bf(a.z); r.u[3] = f2bf(a.w);
    r.u[4] = f2bf(b.x); r.u[5] = f2bf(b.y); r.u[6] = f2bf(b.z); r.u[7] = f2bf(b.w);
    ((uint4*)out)[i] = r.v;
}

// ---------------------------------------------------------------------------
// fp32 [K][N] -> bf16 [N][K] transpose-convert, 64x64 tiles
// ---------------------------------------------------------------------------
__global__ __launch_bounds__(256) void cvtT(const float* __restrict__ in,
                                            u16* __restrict__ out, int K, int N) {
    __shared__ u16 t[64][72];
    const int n0 = blockIdx.x * 64, k0 = blockIdx.y * 64;
    const int tid = threadIdx.x;
    const int r = tid >> 2, c0 = (tid & 3) << 4;
    const float* src = in + (size_t)(k0 + r) * N + n0 + c0;
#pragma unroll
    for (int j = 0; j < 16; j += 4) {
        float4 f = *(const float4*)(src + j);
        t[r][c0 + j + 0] = f2bf(f.x);
        t[r][c0 + j + 1] = f2bf(f.y);
        t[r][c0 + j + 2] = f2bf(f.z);
        t[r][c0 + j + 3] = f2bf(f.w);
    }
    __syncthreads();
    u16* dst = out + (size_t)(n0 + r) * K + k0 + c0;
    union { u16 u[8]; uint4 v; } o1, o2;
#pragma unroll
    for (int j = 0; j < 8; ++j) o1.u[j] = t[c0 + j][r];
#pragma unroll
    for (int j = 0; j < 8; ++j) o2.u[j] = t[c0 + 8 + j][r];
    *(uint4*)dst = o1.v;
    *(uint4*)(dst + 8) = o2.v;
}

// ---------------------------------------------------------------------------
// QKV GEMM: [8192,1024]bf16 @ [1024,3072] (B^T layout [3072][1024]) -> q/k/vT
// 128x128 tile, BK=32, 4 waves (2x2 quadrants of 64x64), 16x16x32 MFMA.
// ---------------------------------------------------------------------------
__global__ __launch_bounds__(256) void qkv_gemm_bf16(
    const u16* __restrict__ xb, const u16* __restrict__ wT,
    const float* __restrict__ bias,
    u16* __restrict__ qo, u16* __restrict__ ko, u16* __restrict__ vt)
{
    __shared__ u16 At[2][4096];
    __shared__ u16 Bt[2][4096];

    const int tid  = threadIdx.x;
    const int lane = tid & 63;
    const int wv   = tid >> 6;
    const int wr   = wv >> 1;
    const int wc   = wv & 1;
    const int m0   = blockIdx.x * 128;
    const int n0   = blockIdx.y * 128;

    const int p1 = wv * 128 + lane, p2 = p1 + 64;
    const int r1 = p1 >> 2, c1 = (p1 & 3) ^ ((r1 >> 1) & 3);
    const int r2 = p2 >> 2, c2 = (p2 & 3) ^ ((r2 >> 1) & 3);

    const u16* ga1 = xb + (size_t)(m0 + r1) * 1024 + c1 * 8;
    const u16* ga2 = xb + (size_t)(m0 + r2) * 1024 + c2 * 8;
    const u16* gb1 = wT + (size_t)(n0 + r1) * 1024 + c1 * 8;
    const u16* gb2 = wT + (size_t)(n0 + r2) * 1024 + c2 * 8;

    f32x4 acc[4][4] = {};

#define STAGE_G(buf, k0)                                   \
    do {                                                   \
        gld_lds16(ga1 + (k0), &At[buf][wv * 1024]);        \
        gld_lds16(ga2 + (k0), &At[buf][wv * 1024 + 512]);  \
        gld_lds16(gb1 + (k0), &Bt[buf][wv * 1024]);        \
        gld_lds16(gb2 + (k0), &Bt[buf][wv * 1024 + 512]);  \
    } while (0)

    STAGE_G(0, 0);
    asm volatile("s_waitcnt vmcnt(0)" ::: "memory");
    __syncthreads();

    int cur = 0;
    for (int t = 0; t < 32; ++t) {
        if (t < 31) STAGE_G(cur ^ 1, (t + 1) * 32);
        bf16x8 af[4], bfr[4];
#pragma unroll
        for (int i = 0; i < 4; ++i) {
            int row = wr * 64 + i * 16 + (lane & 15);
            int c   = (lane >> 4) ^ ((row >> 1) & 3);
            af[i] = *(const bf16x8*)&At[cur][row * 32 + c * 8];
            int rowb = wc * 64 + i * 16 + (lane & 15);
            int cb   = (lane >> 4) ^ ((rowb >> 1) & 3);
            bfr[i] = *(const bf16x8*)&Bt[cur][rowb * 32 + cb * 8];
        }
#pragma unroll
        for (int i = 0; i < 4; ++i)
#pragma unroll
            for (int j = 0; j < 4; ++j)
                acc[i][j] = __builtin_amdgcn_mfma_f32_16x16x32_bf16(
                    af[i], bfr[j], acc[i][j], 0, 0, 0);
        asm volatile("s_waitcnt vmcnt(0)" ::: "memory");
        __syncthreads();
        cur ^= 1;
    }
#undef STAGE_G

    const int nq = n0 + wc * 64;
    const int which = nq >> 10;
    const int h  = (nq & 1023) >> 6;
    const int rr = (lane >> 4) * 4;
    const int cl = lane & 15;

    if (which < 2) {
        u16* dst = which ? ko : qo;
#pragma unroll
        for (int i = 0; i < 4; ++i)
#pragma unroll
            for (int j = 0; j < 4; ++j) {
                int d = j * 16 + cl;
                float bv = bias[nq + d];
#pragma unroll
                for (int r = 0; r < 4; ++r) {
                    int m = m0 + wr * 64 + i * 16 + rr + r;
                    int b = m >> 11, tt = m & 2047;
                    dst[(((size_t)(b * Hc + h)) * Tc + tt) * 64 + d] =
                        f2bf(acc[i][j][r] + bv);
                }
            }
    } else {
        // V stored TRANSPOSED: vt[bh][d][t]
#pragma unroll
        for (int i = 0; i < 4; ++i) {
            int m = m0 + wr * 64 + i * 16 + rr;
            int b = m >> 11, tt = m & 2047;
#pragma unroll
            for (int j = 0; j < 4; ++j) {
                int d = j * 16 + cl;
                float bv = bias[nq + d];
                union { u16 u[4]; uint2 v2; } pk;
#pragma unroll
                for (int r = 0; r < 4; ++r) pk.u[r] = f2bf(acc[i][j][r] + bv);
                *(uint2*)&vt[((size_t)(b * Hc + h) * 64 + d) * Tc + tt] = pk.v2;
            }
        }
    }
}

// ---------------------------------------------------------------------------
// Flash attention v2: block = 128 q-rows (32/wave), K/V tiles of 64 keys,
// Q pre-scaled (x0.125, exact) and hoisted to registers. K/V double-buffered
// swizzled LDS (col16 ^= row&7); P per-wave swizzled LDS. 48 KB -> 3 blk/CU.
// ---------------------------------------------------------------------------
__global__ __launch_bounds__(256, 3) void flash_mfma(
    const u16* __restrict__ qg, const u16* __restrict__ kg,
    const u16* __restrict__ vtg, u16* __restrict__ og)
{
    __shared__ u16 Ks[2][4096];
    __shared__ u16 Vs[2][4096];
    __shared__ u16 Ps[8192];     // 4 waves x 32 rows x 64 (swizzled)

    const int tid  = threadIdx.x;
    const int lane = tid & 63;
    const int wv   = tid >> 6;
    const int qb   = 15 - (int)(blockIdx.x >> 6);   // qb-major, heavy first
    const int bh   = blockIdx.x & 63;

    // staging: chunk p -> row=p>>3, cp=p&7, col16 = cp ^ (row&7)
    const int p1 = wv * 128 + lane, p2 = p1 + 64;
    const int r1 = p1 >> 3, c1 = (p1 & 7) ^ (r1 & 7);
    const int r2 = p2 >> 3, c2 = (p2 & 7) ^ (r2 & 7);

    const size_t tb = (size_t)bh * Tc;
    const u16* kb1 = kg + (tb + r1) * 64 + c1 * 8;
    const u16* kb2 = kg + (tb + r2) * 64 + c2 * 8;
    const u16* vb1 = vtg + ((size_t)bh * 64 + r1) * Tc + c1 * 8;
    const u16* vb2 = vtg + ((size_t)bh * 64 + r2) * Tc + c2 * 8;

    // ---- Q -> registers, pre-scaled by 1/8 (exact in bf16)
    bf16x8 qr[2][2];
    {
        const u16* qbase = qg + (tb + (size_t)qb * 128 + wv * 32) * 64;
#pragma unroll
        for (int ar = 0; ar < 2; ++ar)
#pragma unroll
            for (int ks = 0; ks < 2; ++ks) {
                union { bf16x8 v; u16 u[8]; uint4 q; } t;
                t.q = *(const uint4*)(qbase + (ar * 16 + (lane & 15)) * 64 +
                                      ks * 32 + (lane >> 4) * 8);
#pragma unroll
                for (int j = 0; j < 8; ++j) {
                    float f = __uint_as_float((unsigned)t.u[j] << 16) * 0.125f;
                    t.u[j] = f2bf(f);
                }
                qr[ar][ks] = t.v;
            }
    }

    gld_lds16(kb1, &Ks[0][wv * 1024]);
    gld_lds16(kb2, &Ks[0][wv * 1024 + 512]);
    gld_lds16(vb1, &Vs[0][wv * 1024]);
    gld_lds16(vb2, &Vs[0][wv * 1024 + 512]);
    asm volatile("s_waitcnt vmcnt(0)" ::: "memory");
    __syncthreads();

    f32x4 accO[2][4] = {};
    float mi[2][4], li[2][4];
#pragma unroll
    for (int a = 0; a < 2; ++a)
#pragma unroll
        for (int r = 0; r < 4; ++r) { mi[a][r] = -INFINITY; li[a][r] = 0.f; }

    const int nt = 2 * qb + 2;
    int cur = 0;

    for (int kt = 0; kt < nt; ++kt) {
        if (kt + 1 < nt) {
            int nx = kt + 1;
            gld_lds16(kb1 + (size_t)nx * 4096, &Ks[cur ^ 1][wv * 1024]);
            gld_lds16(kb2 + (size_t)nx * 4096, &Ks[cur ^ 1][wv * 1024 + 512]);
            gld_lds16(vb1 + nx * 64, &Vs[cur ^ 1][wv * 1024]);
            gld_lds16(vb2 + nx * 64, &Vs[cur ^ 1][wv * 1024 + 512]);
        }

        // waves 0/1 are fully masked on the final (odd) diagonal tile
        const bool skip = (kt == 2 * qb + 1) && (wv < 2);
        if (!skip) {
            // ---- S = Q K^T : per wave 32 q-rows x 64 keys
            f32x4 s4[2][4] = {};
#pragma unroll
            for (int ks = 0; ks < 2; ++ks) {
                bf16x8 bk[4];
#pragma unroll
                for (int nf = 0; nf < 4; ++nf) {
                    int brow = nf * 16 + (lane & 15);
                    int bc   = (ks * 4 + (lane >> 4)) ^ (brow & 7);
                    bk[nf] = *(const bf16x8*)&Ks[cur][brow * 64 + bc * 8];
                }
#pragma unroll
                for (int ar = 0; ar < 2; ++ar)
#pragma unroll
                    for (int nf = 0; nf < 4; ++nf)
                        s4[ar][nf] = __builtin_amdgcn_mfma_f32_16x16x32_bf16(
                            qr[ar][ks], bk[nf], s4[ar][nf], 0, 0, 0);
            }

            if (kt >= 2 * qb) {   // diagonal region: mask key > q
#pragma unroll
                for (int ar = 0; ar < 2; ++ar)
#pragma unroll
                    for (int nf = 0; nf < 4; ++nf)
#pragma unroll
                        for (int r = 0; r < 4; ++r) {
                            int key  = kt * 64 + nf * 16 + (lane & 15);
                            int qrow = qb * 128 + wv * 32 + ar * 16 +
                                       (lane >> 4) * 4 + r;
                            if (key > qrow) s4[ar][nf][r] = -INFINITY;
                        }
            }

            // ---- online softmax (rows owned by 16-lane groups)
#pragma unroll
            for (int ar = 0; ar < 2; ++ar)
#pragma unroll
                for (int r = 0; r < 4; ++r) {
                    float v0 = s4[ar][0][r], v1 = s4[ar][1][r];
                    float v2 = s4[ar][2][r], v3 = s4[ar][3][r];
                    float rm = fmaxf(fmaxf(v0, v1), fmaxf(v2, v3));
#pragma unroll
                    for (int off = 8; off; off >>= 1)
                        rm = fmaxf(rm, __shfl_xor(rm, off, 16));
                    float mnew = fmaxf(mi[ar][r], rm);
                    float sc = __expf(mi[ar][r] - mnew);
                    float pv0 = __expf(v0 - mnew), pv1 = __expf(v1 - mnew);
                    float pv2 = __expf(v2 - mnew), pv3 = __expf(v3 - mnew);
                    float rs = pv0 + pv1 + pv2 + pv3;
#pragma unroll
                    for (int off = 8; off; off >>= 1)
                        rs += __shfl_xor(rs, off, 16);
                    li[ar][r] = li[ar][r] * sc + rs;
                    mi[ar][r] = mnew;
#pragma unroll
                    for (int df = 0; df < 4; ++df) accO[ar][df][r] *= sc;

                    int lrow = ar * 16 + (lane >> 4) * 4 + r;
                    int rb   = wv * 2048 + lrow * 64;
                    int k0c  = lane & 15;
                    Ps[rb + (((0 * 16 + k0c) >> 3) ^ (lrow & 7)) * 8 + (k0c & 7)] = f2bf(pv0);
                    Ps[rb + (((1 * 16 + k0c) >> 3) ^ (lrow & 7)) * 8 + (k0c & 7)] = f2bf(pv1);
                    Ps[rb + (((2 * 16 + k0c) >> 3) ^ (lrow & 7)) * 8 + (k0c & 7)] = f2bf(pv2);
                    Ps[rb + (((3 * 16 + k0c) >> 3) ^ (lrow & 7)) * 8 + (k0c & 7)] = f2bf(pv3);
                }

            // ---- O += P V  (k-dim = keys); P reads are wave-local
#pragma unroll
            for (int ks = 0; ks < 2; ++ks) {
                bf16x8 ap[2];
#pragma unroll
                for (int ar = 0; ar < 2; ++ar) {
                    int arow = ar * 16 + (lane & 15);
                    int ac   = (ks * 4 + (lane >> 4)) ^ (arow & 7);
                    ap[ar] = *(const bf16x8*)&Ps[wv * 2048 + arow * 64 + ac * 8];
                }
#pragma unroll
                for (int df = 0; df < 4; ++df) {
                    int brow = df * 16 + (lane & 15);
                    int bc   = (ks * 4 + (lane >> 4)) ^ (brow & 7);
                    bf16x8 bv = *(const bf16x8*)&Vs[cur][brow * 64 + bc * 8];
#pragma unroll
                    for (int ar = 0; ar < 2; ++ar)
                        accO[ar][df] = __builtin_amdgcn_mfma_f32_16x16x32_bf16(
                            ap[ar], bv, accO[ar][df], 0, 0, 0);
                }
            }
        }

        asm volatile("s_waitcnt vmcnt(0)" ::: "memory");
        __syncthreads();
        cur ^= 1;
    }

#pragma unroll
    for (int ar = 0; ar < 2; ++ar)
#pragma unroll
        for (int r = 0; r < 4; ++r) {
            float inv = 1.0f / li[ar][r];
            int t = qb * 128 + wv * 32 + ar * 16 + (lane >> 4) * 4 + r;
#pragma unroll
            for (int df = 0; df < 4; ++df) {
                int d = df * 16 + (lane & 15);
                og[(tb + t) * 64 + d] = f2bf(accO[ar][df][r] * inv);
            }
        }
}

// ---------------------------------------------------------------------------
// Proj GEMM: gather(O [bh][t][64]) @ w_projT [1024][1024] + b -> out fp32
// ---------------------------------------------------------------------------
__global__ __launch_bounds__(256) void proj_gemm_bf16(
    const u16* __restrict__ ob, const u16* __restrict__ wT,
    const float* __restrict__ bias, float* __restrict__ out)
{
    __shared__ u16 At[2][4096];
    __shared__ u16 Bt[2][4096];

    const int tid  = threadIdx.x;
    const int lane = tid & 63;
    const int wv   = tid >> 6;
    const int wr   = wv >> 1;
    const int wc   = wv & 1;
    const int m0   = blockIdx.x * 128;
    const int n0   = blockIdx.y * 128;

    const int p1 = wv * 128 + lane, p2 = p1 + 64;
    const int r1 = p1 >> 2, c1 = (p1 & 3) ^ ((r1 >> 1) & 3);
    const int r2 = p2 >> 2, c2 = (p2 & 3) ^ ((r2 >> 1) & 3);

    const int m1 = m0 + r1, m2 = m0 + r2;
    const size_t ab1 = ((size_t)(m1 >> 11) * Hc) * Tc + (m1 & 2047);
    const size_t ab2 = ((size_t)(m2 >> 11) * Hc) * Tc + (m2 & 2047);
    const u16* gb1 = wT + (size_t)(n0 + r1) * 1024 + c1 * 8;
    const u16* gb2 = wT + (size_t)(n0 + r2) * 1024 + c2 * 8;

    f32x4 acc[4][4] = {};

#define STAGE_P(buf, k0)                                                          \
    do {                                                                          \
        int kk1 = (k0) + c1 * 8, kk2 = (k0) + c2 * 8;                             \
        gld_lds16(ob + (ab1 + (size_t)(kk1 >> 6) * Tc) * 64 + (kk1 & 63),         \
                  &At[buf][wv * 1024]);                                           \
        gld_lds16(ob + (ab2 + (size_t)(kk2 >> 6) * Tc) * 64 + (kk2 & 63),         \
                  &At[buf][wv * 1024 + 512]);                                     \
        gld_lds16(gb1 + (k0), &Bt[buf][wv * 1024]);                               \
        gld_lds16(gb2 + (k0), &Bt[buf][wv * 1024 + 512]);                         \
    } while (0)

    STAGE_P(0, 0);
    asm volatile("s_waitcnt vmcnt(0)" ::: "memory");
    __syncthreads();

    int cur = 0;
    for (int t = 0; t < 32; ++t) {
        if (t < 31) STAGE_P(cur ^ 1, (t + 1) * 32);
        bf16x8 af[4], bfr[4];
#pragma unroll
        for (int i = 0; i < 4; ++i) {
            int row = wr * 64 + i * 16 + (lane & 15);
            int c   = (lane >> 4) ^ ((row >> 1) & 3);
            af[i] = *(const bf16x8*)&At[cur][row * 32 + c * 8];
            int rowb = wc * 64 + i * 16 + (lane & 15);
            int cb   = (lane >> 4) ^ ((rowb >> 1) & 3);
            bfr[i] = *(const bf16x8*)&Bt[cur][rowb * 32 + cb * 8];
        }
#pragma unroll
        for (int i = 0; i < 4; ++i)
#pragma unroll
            for (int j = 0; j < 4; ++j)
                acc[i][j] = __builtin_amdgcn_mfma_f32_16x16x32_bf16(
                    af[i], bfr[j], acc[i][j], 0, 0, 0);
        asm volatile("s_waitcnt vmcnt(0)" ::: "memory");
        __syncthreads();
        cur ^= 1;
    }
#undef STAGE_P

    const int rr = (lane >> 4) * 4;
    const int cl = lane & 15;
#pragma unroll
    for (int i = 0; i < 4; ++i)
#pragma unroll
        for (int j = 0; j < 4; ++j) {
            int n = n0 + wc * 64 + j * 16 + cl;
            float bv = bias[n];
#pragma unroll
            for (int r = 0; r < 4; ++r) {
                int m = m0 + wr * 64 + i * 16 + rr + r;
                out[(size_t)m * 1024 + n] = acc[i][j][r] + bv;
            }
        }
}

// ---------------------------------------------------------------------------
extern "C" void kernel_launch(void* const* d_in, const int* in_sizes, int n_in,
                              void* d_out, int out_size, void* d_ws, size_t ws_size,
                              hipStream_t stream) {
    const float* x      = (const float*)d_in[0];
    const float* w_qkv  = (const float*)d_in[1];
    const float* b_qkv  = (const float*)d_in[2];
    const float* w_proj = (const float*)d_in[3];
    const float* b_proj = (const float*)d_in[4];
    float* out = (float*)d_out;

    u16* xb     = (u16*)d_ws;            // 16 MiB
    u16* wqkvT  = xb + QE;               // 6 MiB
    u16* wprojT = wqkvT + 3145728;       // 2 MiB
    u16* qb16   = wprojT + 1048576;      // 16 MiB
    u16* kb16   = qb16 + QE;             // 16 MiB
    u16* vtb    = kb16 + QE;             // 16 MiB (V transposed [bh][d][t])
    u16* ob16   = vtb + QE;              // 16 MiB — total 88 MiB

    cvt_bf16<<<4096, 256, 0, stream>>>(x, xb, 1048576);
    cvtT<<<dim3(48, 16), 256, 0, stream>>>(w_qkv, wqkvT, 1024, 3072);
    cvtT<<<dim3(16, 16), 256, 0, stream>>>(w_proj, wprojT, 1024, 1024);
    qkv_gemm_bf16<<<dim3(64, 24), 256, 0, stream>>>(xb, wqkvT, b_qkv, qb16, kb16, vtb);
    flash_mfma<<<1024, 256, 0, stream>>>(qb16, kb16, vtb, ob16);
    proj_gemm_bf16<<<dim3(64, 8), 256, 0, stream>>>(ob16, wprojT, b_proj, out);
}